// Round 6
// baseline (332.678 us; speedup 1.0000x reference)
//
#include <hip/hip_runtime.h>
#include <math.h>

typedef _Float16 h8 __attribute__((ext_vector_type(8)));
typedef _Float16 h2 __attribute__((ext_vector_type(2)));
typedef float    f4 __attribute__((ext_vector_type(4)));

#define NPAIR (8*256*256)
#define NTILE (NPAIR/16)          // 32768 tiles of 16 rows
#define BLOCKS 2048
#define ITERS (NTILE/(BLOCKS*4))  // 4 tiles per wave

#define MFMA(a,b,c) __builtin_amdgcn_mfma_f32_16x16x32_f16((a),(b),(c),0,0,0)

// All weight fragments packed into one global array (h8 units):
// [0,256)    W1   [t*64+lane]          k 9..31 zero-padded
// [256,768)  W2   [c*256+t*64+lane]    k = 32c+8q+j
// [768,896)  Wg2  [c*64+lane]          n>=2 zero-padded
// [896,1920) Wg1  [c*256+t*64+lane]    k = 32c+8q+j (128 rows)
__device__ h8 g_all[1920];
__device__ float g_cc[2];         // C0 = sum ln_b*Wo, C1 = sum ln_g*Wo

__global__ void prep_kernel(const float* __restrict__ W1, const float* __restrict__ W2,
                            const float* __restrict__ Wg1, const float* __restrict__ Wg2,
                            const float* __restrict__ ln_g, const float* __restrict__ ln_b,
                            const float* __restrict__ Wo)
{
    int idx = blockIdx.x * 256 + threadIdx.x;
    if (idx < 256) {
        int t = idx >> 6, lane = idx & 63, q = lane >> 4, nn = lane & 15;
        h8 v;
#pragma unroll
        for (int j = 0; j < 8; ++j) { int k = 8*q + j; v[j] = (_Float16)((k < 9) ? W1[k*64 + 16*t + nn] : 0.f); }
        g_all[idx] = v;
    } else if (idx < 768) {
        int z = idx - 256; int c = z >> 8, t = (z >> 6) & 3, lane = z & 63, q = lane >> 4, nn = lane & 15;
        h8 v;
#pragma unroll
        for (int j = 0; j < 8; ++j) { int k = 32*c + 8*q + j; v[j] = (_Float16)W2[k*64 + 16*t + nn]; }
        g_all[idx] = v;
    } else if (idx < 896) {
        int z = idx - 768; int c = z >> 6, lane = z & 63, q = lane >> 4, nn = lane & 15;
        h8 v;
#pragma unroll
        for (int j = 0; j < 8; ++j) { int k = 32*c + 8*q + j; v[j] = (_Float16)((nn < 2) ? Wg2[k*2 + nn] : 0.f); }
        g_all[idx] = v;
    } else if (idx < 1920) {
        int z = idx - 896; int c = z >> 8, t = (z >> 6) & 3, lane = z & 63, q = lane >> 4, nn = lane & 15;
        h8 v;
#pragma unroll
        for (int j = 0; j < 8; ++j) { int k = 32*c + 8*q + j; v[j] = (_Float16)Wg1[k*64 + 16*t + nn]; }
        g_all[idx] = v;
    } else if (idx == 1920) {
        float c0 = 0.f, c1 = 0.f;
        for (int k = 0; k < 64; ++k) { c0 += ln_b[k]*Wo[k]; c1 += ln_g[k]*Wo[k]; }
        g_cc[0] = c0; g_cc[1] = c1;
    }
}

__device__ __forceinline__ float sig(float x) { return __builtin_amdgcn_rcpf(1.f + __expf(-x)); }

__device__ __forceinline__ f4 silu4(f4 v)
{
    f4 r; r[0] = v[0]*sig(v[0]); r[1] = v[1]*sig(v[1]); r[2] = v[2]*sig(v[2]); r[3] = v[3]*sig(v[3]);
    return r;
}

__device__ __forceinline__ f4 reduce16(f4 v)  // sum over the 16 lanes of each 16-group
{
#pragma unroll
    for (int m = 1; m < 16; m <<= 1) {
        v[0] += __shfl_xor(v[0], m); v[1] += __shfl_xor(v[1], m);
        v[2] += __shfl_xor(v[2], m); v[3] += __shfl_xor(v[3], m);
    }
    return v;
}

__device__ __forceinline__ void st72(_Float16* p, f4 v)   // C-frag -> LDS row stride 72 (144B, 16B-aligned rows)
{ p[0] = (_Float16)v[0]; p[72] = (_Float16)v[1]; p[144] = (_Float16)v[2]; p[216] = (_Float16)v[3]; }

__device__ __forceinline__ void st136(_Float16* p, f4 v)  // row stride 136
{ p[0] = (_Float16)v[0]; p[136] = (_Float16)v[1]; p[272] = (_Float16)v[2]; p[408] = (_Float16)v[3]; }

// LDS: 16384 B Wg1 pool (block-shared) + 4 waves * 4608 B aliased scratch.
// feat (2560B) / h (4608B) / e (4352B) / g (2304B) all ALIAS one wave region:
// DS ops are wave-ordered and each stage's reads precede the next stage's
// writes in program order. feat rows are written as full zero-padded h8x4.
// Total 34816 B -> 4 blocks/CU = 16 waves/CU at VGPR<=128 (R4: 62976 -> 2
// blocks, occ 20%; R5's reg-pressure experiment spilled -> scratch-bound).
__global__ __launch_bounds__(256, 4) void fused_kernel(
    const float* __restrict__ coords, const float* __restrict__ cost,
    const float* __restrict__ lscale, const float* __restrict__ b1,
    const float* __restrict__ b2, const float* __restrict__ fgam,
    const float* __restrict__ fbet, const float* __restrict__ bg1,
    const float* __restrict__ bg2, const float* __restrict__ gt,
    const float* __restrict__ lng, const float* __restrict__ Wo,
    const float* __restrict__ bo, float* __restrict__ out)
{
    __shared__ __align__(16) char smem[16384 + 4*4608];
    const int tid = threadIdx.x;
    const int wave = tid >> 6, lane = tid & 63;
    const int q = lane >> 4, nn = lane & 15;

    h8* wgv = (h8*)smem;                      // 1024 h8 = 16 KB: Wg1 frags
    for (int z = tid; z < 1024; z += 256) wgv[z] = g_all[896 + z];
    __syncthreads();

    _Float16* U = (_Float16*)(smem + 16384 + wave*4608);  // aliased feat/h/e/g

    // register-resident B-frags (56 VGPRs)
    h8 w1f0 = g_all[lane],      w1f1 = g_all[64+lane],  w1f2 = g_all[128+lane], w1f3 = g_all[192+lane];
    h8 w2f00 = g_all[256+lane], w2f01 = g_all[320+lane], w2f02 = g_all[384+lane], w2f03 = g_all[448+lane];
    h8 w2f10 = g_all[512+lane], w2f11 = g_all[576+lane], w2f12 = g_all[640+lane], w2f13 = g_all[704+lane];
    h8 wg2f0 = g_all[768+lane], wg2f1 = g_all[832+lane];

    const float b1c0 = b1[nn], b1c1 = b1[16+nn], b1c2 = b1[32+nn], b1c3 = b1[48+nn];
    const float b2c0 = b2[nn], b2c1 = b2[16+nn], b2c2 = b2[32+nn], b2c3 = b2[48+nn];
    const float bgc0 = bg1[nn], bgc1 = bg1[16+nn], bgc2 = bg1[32+nn], bgc3 = bg1[48+nn];
    const float fg00 = fgam[nn], fg01 = fgam[16+nn], fg02 = fgam[32+nn], fg03 = fgam[48+nn];
    const float fg10 = fgam[64+nn], fg11 = fgam[80+nn], fg12 = fgam[96+nn], fg13 = fgam[112+nn];
    const float fb00 = fbet[nn], fb01 = fbet[16+nn], fb02 = fbet[32+nn], fb03 = fbet[48+nn];
    const float fb10 = fbet[64+nn], fb11 = fbet[80+nn], fb12 = fbet[96+nn], fb13 = fbet[112+nn];
    const float gw0 = lng[nn]*Wo[nn], gw1 = lng[16+nn]*Wo[16+nn];
    const float gw2 = lng[32+nn]*Wo[32+nn], gw3 = lng[48+nn]*Wo[48+nn];
    const float s0 = __expf(lscale[0]), s1 = __expf(lscale[1]);
    const float invT = __expf(-gt[0]);
    const float outc = g_cc[0] + bo[0], C1 = g_cc[1];
    const float lgb = (nn < 2) ? bg2[nn] : 0.f;

    const int wgid = blockIdx.x*4 + wave;

    for (int it = 0; it < ITERS; ++it) {
        const int T = wgid + it*(BLOCKS*4);
        const int p0 = T*16;
        const int bb = p0 >> 16, ii = (p0 >> 8) & 255, j0 = p0 & 255;
        // ---- features: lanes 0-15 cost channel, 16-31 angle channel ----
        const float xc = cost[p0 + nn];
        const float* cb = coords + (bb << 9);
        const float xi = cb[2*ii], yi = cb[2*ii+1];
        const float xj = cb[2*(j0+nn)], yj = cb[2*(j0+nn)+1];
        const float ang = atan2f(yi - yj, xi - xj);
        const int isA = q & 1;
        const float xv = isA ? ang : xc;
        const float sE = isA ? s1 : s0;
        const float F0 = xv*sE;
        const float sn1 = __sinf(xv)*sE,      cs1 = __cosf(xv)*sE;
        const float sn2 = __sinf(2.f*xv)*sE,  cs2 = __cosf(2.f*xv)*sE;
        const float sn4 = __sinf(4.f*xv)*sE,  cs4 = __cosf(4.f*xv)*sE;
        const float sn8 = __sinf(8.f*xv)*sE,  cs8 = __cosf(8.f*xv)*sE;
        if (lane < 32) {
            // full 32-half zero-padded row: pads rewritten every iter (region aliased)
            _Float16* fp = U + isA*640 + nn*40;
            h8 r0; r0[0]=(_Float16)F0;  r0[1]=(_Float16)sn1; r0[2]=(_Float16)cs1;
                   r0[3]=(_Float16)sn2; r0[4]=(_Float16)cs2; r0[5]=(_Float16)sn4;
                   r0[6]=(_Float16)cs4; r0[7]=(_Float16)sn8;
            h8 rz = (h8)(_Float16)0.f;
            h8 r1 = rz; r1[0]=(_Float16)cs8;
            *(h8*)(fp)    = r0; *(h8*)(fp+8)  = r1;
            *(h8*)(fp+16) = rz; *(h8*)(fp+24) = rz;
        }
        // ---- L1: feats(16 pad 32) @ W1 -> silu -> h tile (aliases feat) ----
        h8 aF0 = *(h8*)(U + nn*40 + q*8);
        h8 aF1 = *(h8*)(U + 640 + nn*40 + q*8);
        _Float16* hw0 = U + q*288 + nn;
        _Float16* hw1 = U + 1152 + q*288 + nn;
        { f4 a = {b1c0,b1c0,b1c0,b1c0}; a = MFMA(aF0, w1f0, a); st72(hw0,    silu4(a)); }
        { f4 a = {b1c1,b1c1,b1c1,b1c1}; a = MFMA(aF0, w1f1, a); st72(hw0+16, silu4(a)); }
        { f4 a = {b1c2,b1c2,b1c2,b1c2}; a = MFMA(aF0, w1f2, a); st72(hw0+32, silu4(a)); }
        { f4 a = {b1c3,b1c3,b1c3,b1c3}; a = MFMA(aF0, w1f3, a); st72(hw0+48, silu4(a)); }
        { f4 a = {b1c0,b1c0,b1c0,b1c0}; a = MFMA(aF1, w1f0, a); st72(hw1,    silu4(a)); }
        { f4 a = {b1c1,b1c1,b1c1,b1c1}; a = MFMA(aF1, w1f1, a); st72(hw1+16, silu4(a)); }
        { f4 a = {b1c2,b1c2,b1c2,b1c2}; a = MFMA(aF1, w1f2, a); st72(hw1+32, silu4(a)); }
        { f4 a = {b1c3,b1c3,b1c3,b1c3}; a = MFMA(aF1, w1f3, a); st72(hw1+48, silu4(a)); }
        // ---- L2: h @ W2 + b2, FiLM; e in f32 frags + f16 into U (aliases h) ----
        h8 a00 = *(h8*)(U + nn*72 + q*8);
        h8 a01 = *(h8*)(U + nn*72 + 32 + q*8);
        h8 a10 = *(h8*)(U + 1152 + nn*72 + q*8);
        h8 a11 = *(h8*)(U + 1152 + nn*72 + 32 + q*8);
        _Float16* ew = U + q*544 + nn;
        f4 e00,e01,e02,e03,e10,e11,e12,e13;
        { f4 a={b2c0,b2c0,b2c0,b2c0}; a=MFMA(a00,w2f00,a); a=MFMA(a01,w2f10,a); e00=a*fg00+fb00; st136(ew,     e00); }
        { f4 a={b2c1,b2c1,b2c1,b2c1}; a=MFMA(a00,w2f01,a); a=MFMA(a01,w2f11,a); e01=a*fg01+fb01; st136(ew+16,  e01); }
        { f4 a={b2c2,b2c2,b2c2,b2c2}; a=MFMA(a00,w2f02,a); a=MFMA(a01,w2f12,a); e02=a*fg02+fb02; st136(ew+32,  e02); }
        { f4 a={b2c3,b2c3,b2c3,b2c3}; a=MFMA(a00,w2f03,a); a=MFMA(a01,w2f13,a); e03=a*fg03+fb03; st136(ew+48,  e03); }
        { f4 a={b2c0,b2c0,b2c0,b2c0}; a=MFMA(a10,w2f00,a); a=MFMA(a11,w2f10,a); e10=a*fg10+fb10; st136(ew+64,  e10); }
        { f4 a={b2c1,b2c1,b2c1,b2c1}; a=MFMA(a10,w2f01,a); a=MFMA(a11,w2f11,a); e11=a*fg11+fb11; st136(ew+80,  e11); }
        { f4 a={b2c2,b2c2,b2c2,b2c2}; a=MFMA(a10,w2f02,a); a=MFMA(a11,w2f12,a); e12=a*fg12+fb12; st136(ew+96,  e12); }
        { f4 a={b2c3,b2c3,b2c3,b2c3}; a=MFMA(a10,w2f03,a); a=MFMA(a11,w2f13,a); e13=a*fg13+fb13; st136(ew+112, e13); }
        // ---- gate1: [e0|e1] @ Wg1 + bg1 -> silu -> g tile (aliases e) ----
        h8 ae0 = *(h8*)(U + nn*136 + q*8);
        h8 ae1 = *(h8*)(U + nn*136 + 32 + q*8);
        h8 ae2 = *(h8*)(U + nn*136 + 64 + q*8);
        h8 ae3 = *(h8*)(U + nn*136 + 96 + q*8);
        _Float16* gw_ = U + q*288 + nn;
        { f4 a={bgc0,bgc0,bgc0,bgc0}; a=MFMA(ae0,wgv[lane],a);     a=MFMA(ae1,wgv[256+lane],a); a=MFMA(ae2,wgv[512+lane],a); a=MFMA(ae3,wgv[768+lane],a); st72(gw_,    silu4(a)); }
        { f4 a={bgc1,bgc1,bgc1,bgc1}; a=MFMA(ae0,wgv[64+lane],a);  a=MFMA(ae1,wgv[320+lane],a); a=MFMA(ae2,wgv[576+lane],a); a=MFMA(ae3,wgv[832+lane],a); st72(gw_+16, silu4(a)); }
        { f4 a={bgc2,bgc2,bgc2,bgc2}; a=MFMA(ae0,wgv[128+lane],a); a=MFMA(ae1,wgv[384+lane],a); a=MFMA(ae2,wgv[640+lane],a); a=MFMA(ae3,wgv[896+lane],a); st72(gw_+32, silu4(a)); }
        { f4 a={bgc3,bgc3,bgc3,bgc3}; a=MFMA(ae0,wgv[192+lane],a); a=MFMA(ae1,wgv[448+lane],a); a=MFMA(ae2,wgv[704+lane],a); a=MFMA(ae3,wgv[960+lane],a); st72(gw_+48, silu4(a)); }
        // ---- gate2: g @ Wg2 (N pad 16); logits broadcast via shfl ----
        h8 ag0 = *(h8*)(U + nn*72 + q*8);
        h8 ag1 = *(h8*)(U + nn*72 + 32 + q*8);
        f4 lg = {lgb, lgb, lgb, lgb};
        lg = MFMA(ag0, wg2f0, lg); lg = MFMA(ag1, wg2f1, lg);
        const int sb = lane & 48;
        f4 w1v;
        w1v[0] = sig((__shfl(lg[0], sb|1) - __shfl(lg[0], sb))*invT);
        w1v[1] = sig((__shfl(lg[1], sb|1) - __shfl(lg[1], sb))*invT);
        w1v[2] = sig((__shfl(lg[2], sb|1) - __shfl(lg[2], sb))*invT);
        w1v[3] = sig((__shfl(lg[3], sb|1) - __shfl(lg[3], sb))*invT);
        // ---- fuse + LayerNorm + head (var = E[x^2] - mu^2) ----
        f4 fu0 = e00 + w1v*(e10-e00);
        f4 fu1 = e01 + w1v*(e11-e01);
        f4 fu2 = e02 + w1v*(e12-e02);
        f4 fu3 = e03 + w1v*(e13-e03);
        f4 sv = reduce16((fu0+fu1)+(fu2+fu3));
        f4 sq = reduce16((fu0*fu0+fu1*fu1)+(fu2*fu2+fu3*fu3));
        f4 dt = reduce16((fu0*gw0 + fu1*gw1) + (fu2*gw2 + fu3*gw3));
        f4 mu = sv * (1.f/64.f);
        f4 vv = sq * (1.f/64.f) - mu*mu;
        f4 rs;
        rs[0] = __builtin_amdgcn_rsqf(vv[0]+1e-5f); rs[1] = __builtin_amdgcn_rsqf(vv[1]+1e-5f);
        rs[2] = __builtin_amdgcn_rsqf(vv[2]+1e-5f); rs[3] = __builtin_amdgcn_rsqf(vv[3]+1e-5f);
        f4 o = rs*(dt - mu*C1) + outc;
        if (nn == 0) *(f4*)(out + p0 + q*4) = o;
    }
}

extern "C" void kernel_launch(void* const* d_in, const int* in_sizes, int n_in,
                              void* d_out, int out_size, void* d_ws, size_t ws_size,
                              hipStream_t stream)
{
    const float* coords = (const float*)d_in[0];
    const float* cost   = (const float*)d_in[1];
    const float* lscale = (const float*)d_in[2];
    const float* W1     = (const float*)d_in[3];
    const float* b1     = (const float*)d_in[4];
    const float* W2     = (const float*)d_in[5];
    const float* b2     = (const float*)d_in[6];
    const float* fg     = (const float*)d_in[7];
    const float* fb     = (const float*)d_in[8];
    const float* Wg1    = (const float*)d_in[9];
    const float* bg1    = (const float*)d_in[10];
    const float* Wg2    = (const float*)d_in[11];
    const float* bg2    = (const float*)d_in[12];
    const float* gt     = (const float*)d_in[13];
    const float* lng    = (const float*)d_in[14];
    const float* lnb    = (const float*)d_in[15];
    const float* Wo     = (const float*)d_in[16];
    const float* bo     = (const float*)d_in[17];
    float* out = (float*)d_out;

    prep_kernel<<<8, 256, 0, stream>>>(W1, W2, Wg1, Wg2, lng, lnb, Wo);
    fused_kernel<<<BLOCKS, 256, 0, stream>>>(
        coords, cost, lscale, b1, b2, fg, fb, bg1, bg2, gt, lng, Wo, bo, out);
}

// Round 7
// 232.854 us; speedup vs baseline: 1.4287x; 1.4287x over previous
//
#include <hip/hip_runtime.h>
#include <math.h>

typedef _Float16 h8 __attribute__((ext_vector_type(8)));
typedef float    f4 __attribute__((ext_vector_type(4)));

#define NPAIR (8*256*256)
#define NTILE (NPAIR/16)          // 32768 tiles of 16 rows
#define BLOCKS 2048
#define NWAVES (BLOCKS*4)         // 8192 waves; 4 tiles/wave, 2 per outer iter
#define OUTER 2

#define MFMA(a,b,c) __builtin_amdgcn_mfma_f32_16x16x32_f16((a),(b),(c),0,0,0)

// All weight fragments packed into one global array (h8 units):
// [0,256)    W1   [t*64+lane]          k 9..31 zero-padded
// [256,768)  W2   [c*256+t*64+lane]    k = 32c+8q+j
// [768,896)  Wg2  [c*64+lane]          n>=2 zero-padded
// [896,1920) Wg1  [c*256+t*64+lane]    k = 32c+8q+j (128 rows)
__device__ h8 g_all[1920];
__device__ float g_cc[2];         // C0 = sum ln_b*Wo, C1 = sum ln_g*Wo

__global__ void prep_kernel(const float* __restrict__ W1, const float* __restrict__ W2,
                            const float* __restrict__ Wg1, const float* __restrict__ Wg2,
                            const float* __restrict__ ln_g, const float* __restrict__ ln_b,
                            const float* __restrict__ Wo)
{
    int idx = blockIdx.x * 256 + threadIdx.x;
    if (idx < 256) {
        int t = idx >> 6, lane = idx & 63, q = lane >> 4, nn = lane & 15;
        h8 v;
#pragma unroll
        for (int j = 0; j < 8; ++j) { int k = 8*q + j; v[j] = (_Float16)((k < 9) ? W1[k*64 + 16*t + nn] : 0.f); }
        g_all[idx] = v;
    } else if (idx < 768) {
        int z = idx - 256; int c = z >> 8, t = (z >> 6) & 3, lane = z & 63, q = lane >> 4, nn = lane & 15;
        h8 v;
#pragma unroll
        for (int j = 0; j < 8; ++j) { int k = 32*c + 8*q + j; v[j] = (_Float16)W2[k*64 + 16*t + nn]; }
        g_all[idx] = v;
    } else if (idx < 896) {
        int z = idx - 768; int c = z >> 6, lane = z & 63, q = lane >> 4, nn = lane & 15;
        h8 v;
#pragma unroll
        for (int j = 0; j < 8; ++j) { int k = 32*c + 8*q + j; v[j] = (_Float16)((nn < 2) ? Wg2[k*2 + nn] : 0.f); }
        g_all[idx] = v;
    } else if (idx < 1920) {
        int z = idx - 896; int c = z >> 8, t = (z >> 6) & 3, lane = z & 63, q = lane >> 4, nn = lane & 15;
        h8 v;
#pragma unroll
        for (int j = 0; j < 8; ++j) { int k = 32*c + 8*q + j; v[j] = (_Float16)Wg1[k*64 + 16*t + nn]; }
        g_all[idx] = v;
    } else if (idx == 1920) {
        float c0 = 0.f, c1 = 0.f;
        for (int k = 0; k < 64; ++k) { c0 += ln_b[k]*Wo[k]; c1 += ln_g[k]*Wo[k]; }
        g_cc[0] = c0; g_cc[1] = c1;
    }
}

__device__ __forceinline__ float sig(float x) { return __builtin_amdgcn_rcpf(1.f + __expf(-x)); }

__device__ __forceinline__ f4 silu4(f4 v)
{
    f4 r; r[0] = v[0]*sig(v[0]); r[1] = v[1]*sig(v[1]); r[2] = v[2]*sig(v[2]); r[3] = v[3]*sig(v[3]);
    return r;
}

__device__ __forceinline__ f4 reduce16(f4 v)
{
#pragma unroll
    for (int m = 1; m < 16; m <<= 1) {
        v[0] += __shfl_xor(v[0], m); v[1] += __shfl_xor(v[1], m);
        v[2] += __shfl_xor(v[2], m); v[3] += __shfl_xor(v[3], m);
    }
    return v;
}

__device__ __forceinline__ void st72(_Float16* p, f4 v)
{ p[0] = (_Float16)v[0]; p[72] = (_Float16)v[1]; p[144] = (_Float16)v[2]; p[216] = (_Float16)v[3]; }

__device__ __forceinline__ void st136(_Float16* p, f4 v)
{ p[0] = (_Float16)v[0]; p[136] = (_Float16)v[1]; p[272] = (_Float16)v[2]; p[408] = (_Float16)v[3]; }

struct EF { f4 x0, x1, x2, x3, y0, y1, y2, y3; };  // named members only (no arrays)

// ---- per-tile stage macros (capture kernel locals; U_ = wave/tile LDS region) ----
#define STAGE_FEAT(U_, xc_, ang_) do {                                          \
    const int isA_ = q & 1;                                                     \
    const float xv_ = isA_ ? (ang_) : (xc_);                                    \
    const float sE_ = isA_ ? s1 : s0;                                           \
    if (lane < 32) {                                                            \
        _Float16* fp_ = (U_) + isA_*640 + nn*40;                                \
        h8 r0_; r0_[0]=(_Float16)(xv_*sE_);                                     \
        r0_[1]=(_Float16)(__sinf(xv_)*sE_);     r0_[2]=(_Float16)(__cosf(xv_)*sE_);     \
        r0_[3]=(_Float16)(__sinf(2.f*xv_)*sE_); r0_[4]=(_Float16)(__cosf(2.f*xv_)*sE_); \
        r0_[5]=(_Float16)(__sinf(4.f*xv_)*sE_); r0_[6]=(_Float16)(__cosf(4.f*xv_)*sE_); \
        r0_[7]=(_Float16)(__sinf(8.f*xv_)*sE_);                                 \
        h8 rz_ = (h8)(_Float16)0.f;                                             \
        h8 r1_ = rz_; r1_[0]=(_Float16)(__cosf(8.f*xv_)*sE_);                   \
        *(h8*)(fp_)    = r0_; *(h8*)(fp_+8)  = r1_;                             \
        *(h8*)(fp_+16) = rz_; *(h8*)(fp_+24) = rz_;                             \
    }                                                                           \
} while(0)

#define STAGE_L1(U_) do {                                                       \
    h8 aF0_ = *(h8*)((U_) + nn*40 + q*8);                                       \
    h8 aF1_ = *(h8*)((U_) + 640 + nn*40 + q*8);                                 \
    _Float16* hw0_ = (U_) + q*288 + nn;                                         \
    _Float16* hw1_ = (U_) + 1152 + q*288 + nn;                                  \
    { f4 a_={b1c0,b1c0,b1c0,b1c0}; a_=MFMA(aF0_,w1f0,a_); st72(hw0_,    silu4(a_)); } \
    { f4 a_={b1c1,b1c1,b1c1,b1c1}; a_=MFMA(aF0_,w1f1,a_); st72(hw0_+16, silu4(a_)); } \
    { f4 a_={b1c2,b1c2,b1c2,b1c2}; a_=MFMA(aF0_,w1f2,a_); st72(hw0_+32, silu4(a_)); } \
    { f4 a_={b1c3,b1c3,b1c3,b1c3}; a_=MFMA(aF0_,w1f3,a_); st72(hw0_+48, silu4(a_)); } \
    { f4 a_={b1c0,b1c0,b1c0,b1c0}; a_=MFMA(aF1_,w1f0,a_); st72(hw1_,    silu4(a_)); } \
    { f4 a_={b1c1,b1c1,b1c1,b1c1}; a_=MFMA(aF1_,w1f1,a_); st72(hw1_+16, silu4(a_)); } \
    { f4 a_={b1c2,b1c2,b1c2,b1c2}; a_=MFMA(aF1_,w1f2,a_); st72(hw1_+32, silu4(a_)); } \
    { f4 a_={b1c3,b1c3,b1c3,b1c3}; a_=MFMA(aF1_,w1f3,a_); st72(hw1_+48, silu4(a_)); } \
} while(0)

#define STAGE_L2(U_, E_) do {                                                   \
    h8 a00_ = *(h8*)((U_) + nn*72 + q*8);                                       \
    h8 a01_ = *(h8*)((U_) + nn*72 + 32 + q*8);                                  \
    h8 a10_ = *(h8*)((U_) + 1152 + nn*72 + q*8);                                \
    h8 a11_ = *(h8*)((U_) + 1152 + nn*72 + 32 + q*8);                           \
    _Float16* ew_ = (U_) + q*544 + nn;                                          \
    { f4 a_={b2c0,b2c0,b2c0,b2c0}; a_=MFMA(a00_,w2f00,a_); a_=MFMA(a01_,w2f10,a_); E_.x0=a_*fg00+fb00; st136(ew_,     E_.x0); } \
    { f4 a_={b2c1,b2c1,b2c1,b2c1}; a_=MFMA(a00_,w2f01,a_); a_=MFMA(a01_,w2f11,a_); E_.x1=a_*fg01+fb01; st136(ew_+16,  E_.x1); } \
    { f4 a_={b2c2,b2c2,b2c2,b2c2}; a_=MFMA(a00_,w2f02,a_); a_=MFMA(a01_,w2f12,a_); E_.x2=a_*fg02+fb02; st136(ew_+32,  E_.x2); } \
    { f4 a_={b2c3,b2c3,b2c3,b2c3}; a_=MFMA(a00_,w2f03,a_); a_=MFMA(a01_,w2f13,a_); E_.x3=a_*fg03+fb03; st136(ew_+48,  E_.x3); } \
    { f4 a_={b2c0,b2c0,b2c0,b2c0}; a_=MFMA(a10_,w2f00,a_); a_=MFMA(a11_,w2f10,a_); E_.y0=a_*fg10+fb10; st136(ew_+64,  E_.y0); } \
    { f4 a_={b2c1,b2c1,b2c1,b2c1}; a_=MFMA(a10_,w2f01,a_); a_=MFMA(a11_,w2f11,a_); E_.y1=a_*fg11+fb11; st136(ew_+80,  E_.y1); } \
    { f4 a_={b2c2,b2c2,b2c2,b2c2}; a_=MFMA(a10_,w2f02,a_); a_=MFMA(a11_,w2f12,a_); E_.y2=a_*fg12+fb12; st136(ew_+96,  E_.y2); } \
    { f4 a_={b2c3,b2c3,b2c3,b2c3}; a_=MFMA(a10_,w2f03,a_); a_=MFMA(a11_,w2f13,a_); E_.y3=a_*fg13+fb13; st136(ew_+112, E_.y3); } \
} while(0)

#define STAGE_G1(U_) do {                                                       \
    h8 ae0_ = *(h8*)((U_) + nn*136 + q*8);                                      \
    h8 ae1_ = *(h8*)((U_) + nn*136 + 32 + q*8);                                 \
    h8 ae2_ = *(h8*)((U_) + nn*136 + 64 + q*8);                                 \
    h8 ae3_ = *(h8*)((U_) + nn*136 + 96 + q*8);                                 \
    _Float16* gp_ = (U_) + q*288 + nn;                                          \
    { f4 a_={bgc0,bgc0,bgc0,bgc0}; a_=MFMA(ae0_,wgv[lane],a_);     a_=MFMA(ae1_,wgv[256+lane],a_); a_=MFMA(ae2_,wgv[512+lane],a_); a_=MFMA(ae3_,wgv[768+lane],a_); st72(gp_,    silu4(a_)); } \
    { f4 a_={bgc1,bgc1,bgc1,bgc1}; a_=MFMA(ae0_,wgv[64+lane],a_);  a_=MFMA(ae1_,wgv[320+lane],a_); a_=MFMA(ae2_,wgv[576+lane],a_); a_=MFMA(ae3_,wgv[832+lane],a_); st72(gp_+16, silu4(a_)); } \
    { f4 a_={bgc2,bgc2,bgc2,bgc2}; a_=MFMA(ae0_,wgv[128+lane],a_); a_=MFMA(ae1_,wgv[384+lane],a_); a_=MFMA(ae2_,wgv[640+lane],a_); a_=MFMA(ae3_,wgv[896+lane],a_); st72(gp_+32, silu4(a_)); } \
    { f4 a_={bgc3,bgc3,bgc3,bgc3}; a_=MFMA(ae0_,wgv[192+lane],a_); a_=MFMA(ae1_,wgv[448+lane],a_); a_=MFMA(ae2_,wgv[704+lane],a_); a_=MFMA(ae3_,wgv[960+lane],a_); st72(gp_+48, silu4(a_)); } \
} while(0)

#define STAGE_TAIL(U_, E_, p0_) do {                                            \
    h8 ag0_ = *(h8*)((U_) + nn*72 + q*8);                                       \
    h8 ag1_ = *(h8*)((U_) + nn*72 + 32 + q*8);                                  \
    f4 lg_ = {lgb, lgb, lgb, lgb};                                              \
    lg_ = MFMA(ag0_, wg2f0, lg_); lg_ = MFMA(ag1_, wg2f1, lg_);                 \
    const int sb_ = lane & 48;                                                  \
    f4 w1v_;                                                                    \
    w1v_[0] = sig((__shfl(lg_[0], sb_|1) - __shfl(lg_[0], sb_))*invT);          \
    w1v_[1] = sig((__shfl(lg_[1], sb_|1) - __shfl(lg_[1], sb_))*invT);          \
    w1v_[2] = sig((__shfl(lg_[2], sb_|1) - __shfl(lg_[2], sb_))*invT);          \
    w1v_[3] = sig((__shfl(lg_[3], sb_|1) - __shfl(lg_[3], sb_))*invT);          \
    f4 fu0_ = E_.x0 + w1v_*(E_.y0-E_.x0);                                       \
    f4 fu1_ = E_.x1 + w1v_*(E_.y1-E_.x1);                                       \
    f4 fu2_ = E_.x2 + w1v_*(E_.y2-E_.x2);                                       \
    f4 fu3_ = E_.x3 + w1v_*(E_.y3-E_.x3);                                       \
    f4 sv_ = reduce16((fu0_+fu1_)+(fu2_+fu3_));                                 \
    f4 sq_ = reduce16((fu0_*fu0_+fu1_*fu1_)+(fu2_*fu2_+fu3_*fu3_));             \
    f4 dt_ = reduce16((fu0_*gw0 + fu1_*gw1) + (fu2_*gw2 + fu3_*gw3));           \
    f4 mu_ = sv_ * (1.f/64.f);                                                  \
    f4 vv_ = sq_ * (1.f/64.f) - mu_*mu_;                                        \
    f4 rs_;                                                                     \
    rs_[0] = __builtin_amdgcn_rsqf(vv_[0]+1e-5f); rs_[1] = __builtin_amdgcn_rsqf(vv_[1]+1e-5f); \
    rs_[2] = __builtin_amdgcn_rsqf(vv_[2]+1e-5f); rs_[3] = __builtin_amdgcn_rsqf(vv_[3]+1e-5f); \
    f4 o_ = rs_*(dt_ - mu_*C1) + outc;                                          \
    if (nn == 0) *(f4*)(out + (p0_) + q*4) = o_;                                \
} while(0)

// LDS: 16384 B Wg1 pool + 4 waves * 2 tiles * 4608 B = 53248 B -> 2 blocks/CU
// (same occupancy as R4). Two-tile interleave: every LDS store->load dep has
// the other tile's full stage between issue and consume (latency hiding via
// ILP, after R5/R6 showed occupancy-via-reg-cap only causes spills).
__global__ __launch_bounds__(256, 2) void fused_kernel(
    const float* __restrict__ coords, const float* __restrict__ cost,
    const float* __restrict__ lscale, const float* __restrict__ b1,
    const float* __restrict__ b2, const float* __restrict__ fgam,
    const float* __restrict__ fbet, const float* __restrict__ bg1,
    const float* __restrict__ bg2, const float* __restrict__ gt,
    const float* __restrict__ lng, const float* __restrict__ Wo,
    const float* __restrict__ bo, float* __restrict__ out)
{
    __shared__ __align__(16) char smem[16384 + 8*4608];
    const int tid = threadIdx.x;
    const int wave = tid >> 6, lane = tid & 63;
    const int q = lane >> 4, nn = lane & 15;

    h8* wgv = (h8*)smem;                      // 1024 h8 = 16 KB: Wg1 frags
    for (int z = tid; z < 1024; z += 256) wgv[z] = g_all[896 + z];
    __syncthreads();

    _Float16* UA = (_Float16*)(smem + 16384 + wave*9216);
    _Float16* UB = UA + 2304;

    // register-resident B-frags (56 VGPRs)
    h8 w1f0 = g_all[lane],      w1f1 = g_all[64+lane],  w1f2 = g_all[128+lane], w1f3 = g_all[192+lane];
    h8 w2f00 = g_all[256+lane], w2f01 = g_all[320+lane], w2f02 = g_all[384+lane], w2f03 = g_all[448+lane];
    h8 w2f10 = g_all[512+lane], w2f11 = g_all[576+lane], w2f12 = g_all[640+lane], w2f13 = g_all[704+lane];
    h8 wg2f0 = g_all[768+lane], wg2f1 = g_all[832+lane];

    const float b1c0 = b1[nn], b1c1 = b1[16+nn], b1c2 = b1[32+nn], b1c3 = b1[48+nn];
    const float b2c0 = b2[nn], b2c1 = b2[16+nn], b2c2 = b2[32+nn], b2c3 = b2[48+nn];
    const float bgc0 = bg1[nn], bgc1 = bg1[16+nn], bgc2 = bg1[32+nn], bgc3 = bg1[48+nn];
    const float fg00 = fgam[nn], fg01 = fgam[16+nn], fg02 = fgam[32+nn], fg03 = fgam[48+nn];
    const float fg10 = fgam[64+nn], fg11 = fgam[80+nn], fg12 = fgam[96+nn], fg13 = fgam[112+nn];
    const float fb00 = fbet[nn], fb01 = fbet[16+nn], fb02 = fbet[32+nn], fb03 = fbet[48+nn];
    const float fb10 = fbet[64+nn], fb11 = fbet[80+nn], fb12 = fbet[96+nn], fb13 = fbet[112+nn];
    const float gw0 = lng[nn]*Wo[nn], gw1 = lng[16+nn]*Wo[16+nn];
    const float gw2 = lng[32+nn]*Wo[32+nn], gw3 = lng[48+nn]*Wo[48+nn];
    const float s0 = __expf(lscale[0]), s1 = __expf(lscale[1]);
    const float invT = __expf(-gt[0]);
    const float outc = g_cc[0] + bo[0], C1 = g_cc[1];
    const float lgb = (nn < 2) ? bg2[nn] : 0.f;

    const int W = blockIdx.x*4 + wave;

    for (int it = 0; it < OUTER; ++it) {
        const int pA = (W + it*(NWAVES*2))*16;
        const int pB = pA + NWAVES*16;
        // ---- hoisted global loads: both tiles' cost + coords issue up front ----
        const int bbA = pA >> 16, iiA = (pA >> 8) & 255, j0A = pA & 255;
        const int bbB = pB >> 16, iiB = (pB >> 8) & 255, j0B = pB & 255;
        const float xcA = cost[pA + nn];
        const float xcB = cost[pB + nn];
        const float* cbA = coords + (bbA << 9);
        const float* cbB = coords + (bbB << 9);
        const float xiA = cbA[2*iiA], yiA = cbA[2*iiA+1];
        const float xjA = cbA[2*(j0A+nn)], yjA = cbA[2*(j0A+nn)+1];
        const float xiB = cbB[2*iiB], yiB = cbB[2*iiB+1];
        const float xjB = cbB[2*(j0B+nn)], yjB = cbB[2*(j0B+nn)+1];
        const float angA = atan2f(yiA - yjA, xiA - xjA);
        const float angB = atan2f(yiB - yjB, xiB - xjB);

        STAGE_FEAT(UA, xcA, angA);
        STAGE_FEAT(UB, xcB, angB);
        STAGE_L1(UA);
        STAGE_L1(UB);
        EF eA, eB;
        STAGE_L2(UA, eA);
        STAGE_L2(UB, eB);
        STAGE_G1(UA);
        STAGE_G1(UB);
        STAGE_TAIL(UA, eA, pA);
        STAGE_TAIL(UB, eB, pB);
    }
}

extern "C" void kernel_launch(void* const* d_in, const int* in_sizes, int n_in,
                              void* d_out, int out_size, void* d_ws, size_t ws_size,
                              hipStream_t stream)
{
    const float* coords = (const float*)d_in[0];
    const float* cost   = (const float*)d_in[1];
    const float* lscale = (const float*)d_in[2];
    const float* W1     = (const float*)d_in[3];
    const float* b1     = (const float*)d_in[4];
    const float* W2     = (const float*)d_in[5];
    const float* b2     = (const float*)d_in[6];
    const float* fg     = (const float*)d_in[7];
    const float* fb     = (const float*)d_in[8];
    const float* Wg1    = (const float*)d_in[9];
    const float* bg1    = (const float*)d_in[10];
    const float* Wg2    = (const float*)d_in[11];
    const float* bg2    = (const float*)d_in[12];
    const float* gt     = (const float*)d_in[13];
    const float* lng    = (const float*)d_in[14];
    const float* lnb    = (const float*)d_in[15];
    const float* Wo     = (const float*)d_in[16];
    const float* bo     = (const float*)d_in[17];
    float* out = (float*)d_out;

    prep_kernel<<<8, 256, 0, stream>>>(W1, W2, Wg1, Wg2, lng, lnb, Wo);
    fused_kernel<<<BLOCKS, 256, 0, stream>>>(
        coords, cost, lscale, b1, b2, fg, fb, bg1, bg2, gt, lng, Wo, bo, out);
}

// Round 8
// 183.552 us; speedup vs baseline: 1.8124x; 1.2686x over previous
//
#include <hip/hip_runtime.h>
#include <math.h>

typedef _Float16 h8 __attribute__((ext_vector_type(8)));
typedef float    f4 __attribute__((ext_vector_type(4)));

#define NPAIR (8*256*256)
#define NTILE (NPAIR/16)          // 32768 tiles of 16 rows
#define BLOCKS 2048
#define ITERS (NTILE/(BLOCKS*4))  // 4 tiles per wave

#define MFMA(a,b,c) __builtin_amdgcn_mfma_f32_16x16x32_f16((a),(b),(c),0,0,0)

// All weight fragments packed into one global array (h8 units):
// [0,256)    W1   [t*64+lane]          k 9..31 zero-padded
// [256,768)  W2   [c*256+t*64+lane]    k = 32c+8q+j
// [768,896)  Wg2  [c*64+lane]          n>=2 zero-padded
// [896,1920) Wg1  [c*256+t*64+lane]    k = 32c+8q+j (128 rows)
__device__ h8 g_all[1920];
__device__ float g_cc[2];         // C0 = sum ln_b*Wo, C1 = sum ln_g*Wo

__global__ void prep_kernel(const float* __restrict__ W1, const float* __restrict__ W2,
                            const float* __restrict__ Wg1, const float* __restrict__ Wg2,
                            const float* __restrict__ ln_g, const float* __restrict__ ln_b,
                            const float* __restrict__ Wo)
{
    int idx = blockIdx.x * 256 + threadIdx.x;
    if (idx < 256) {
        int t = idx >> 6, lane = idx & 63, q = lane >> 4, nn = lane & 15;
        h8 v;
#pragma unroll
        for (int j = 0; j < 8; ++j) { int k = 8*q + j; v[j] = (_Float16)((k < 9) ? W1[k*64 + 16*t + nn] : 0.f); }
        g_all[idx] = v;
    } else if (idx < 768) {
        int z = idx - 256; int c = z >> 8, t = (z >> 6) & 3, lane = z & 63, q = lane >> 4, nn = lane & 15;
        h8 v;
#pragma unroll
        for (int j = 0; j < 8; ++j) { int k = 32*c + 8*q + j; v[j] = (_Float16)W2[k*64 + 16*t + nn]; }
        g_all[idx] = v;
    } else if (idx < 896) {
        int z = idx - 768; int c = z >> 6, lane = z & 63, q = lane >> 4, nn = lane & 15;
        h8 v;
#pragma unroll
        for (int j = 0; j < 8; ++j) { int k = 32*c + 8*q + j; v[j] = (_Float16)((nn < 2) ? Wg2[k*2 + nn] : 0.f); }
        g_all[idx] = v;
    } else if (idx < 1920) {
        int z = idx - 896; int c = z >> 8, t = (z >> 6) & 3, lane = z & 63, q = lane >> 4, nn = lane & 15;
        h8 v;
#pragma unroll
        for (int j = 0; j < 8; ++j) { int k = 32*c + 8*q + j; v[j] = (_Float16)Wg1[k*64 + 16*t + nn]; }
        g_all[idx] = v;
    } else if (idx == 1920) {
        float c0 = 0.f, c1 = 0.f;
        for (int k = 0; k < 64; ++k) { c0 += ln_b[k]*Wo[k]; c1 += ln_g[k]*Wo[k]; }
        g_cc[0] = c0; g_cc[1] = c1;
    }
}

__device__ __forceinline__ float sig(float x) { return __builtin_amdgcn_rcpf(1.f + __expf(-x)); }

__device__ __forceinline__ f4 silu4(f4 v)
{
    f4 r; r[0] = v[0]*sig(v[0]); r[1] = v[1]*sig(v[1]); r[2] = v[2]*sig(v[2]); r[3] = v[3]*sig(v[3]);
    return r;
}

__device__ __forceinline__ f4 reduce16(f4 v)  // sum over the 16 lanes of each 16-group
{
#pragma unroll
    for (int m = 1; m < 16; m <<= 1) {
        v[0] += __shfl_xor(v[0], m); v[1] += __shfl_xor(v[1], m);
        v[2] += __shfl_xor(v[2], m); v[3] += __shfl_xor(v[3], m);
    }
    return v;
}

__device__ __forceinline__ void st72(_Float16* p, f4 v)   // C-frag -> LDS row stride 72
{ p[0] = (_Float16)v[0]; p[72] = (_Float16)v[1]; p[144] = (_Float16)v[2]; p[216] = (_Float16)v[3]; }

__device__ __forceinline__ void st136(_Float16* p, f4 v)  // row stride 136
{ p[0] = (_Float16)v[0]; p[136] = (_Float16)v[1]; p[272] = (_Float16)v[2]; p[408] = (_Float16)v[3]; }

// LDS: 16384 B Wg1 pool (block-shared) + 4 waves * 4608 B aliased scratch
// = 34816 B -> LDS allows 4 blocks/CU. KEY (R4-R7 evidence): this kernel's
// allocator ceiling is 128 arch VGPRs — bounds(256,2) is the only setting
// that compiles spill-free (R4: VGPR=128, WRITE=2MB; bounds>=3 forced 64-84
// VGPR + 100s of MB scratch). bounds is only a compiler cap: at VGPR=128 the
// HW scheduler still places 4 blocks/CU (16 waves) since both LDS and VGPR
// budgets allow it — double R4's residency with identical per-wave code.
__global__ __launch_bounds__(256, 2) void fused_kernel(
    const float* __restrict__ coords, const float* __restrict__ cost,
    const float* __restrict__ lscale, const float* __restrict__ b1,
    const float* __restrict__ b2, const float* __restrict__ fgam,
    const float* __restrict__ fbet, const float* __restrict__ bg1,
    const float* __restrict__ bg2, const float* __restrict__ gt,
    const float* __restrict__ lng, const float* __restrict__ Wo,
    const float* __restrict__ bo, float* __restrict__ out)
{
    __shared__ __align__(16) char smem[16384 + 4*4608];
    const int tid = threadIdx.x;
    const int wave = tid >> 6, lane = tid & 63;
    const int q = lane >> 4, nn = lane & 15;

    h8* wgv = (h8*)smem;                      // 1024 h8 = 16 KB: Wg1 frags
    for (int z = tid; z < 1024; z += 256) wgv[z] = g_all[896 + z];
    __syncthreads();

    _Float16* U = (_Float16*)(smem + 16384 + wave*4608);  // aliased feat/h/e/g

    // register-resident B-frags (56 VGPRs)
    h8 w1f0 = g_all[lane],      w1f1 = g_all[64+lane],  w1f2 = g_all[128+lane], w1f3 = g_all[192+lane];
    h8 w2f00 = g_all[256+lane], w2f01 = g_all[320+lane], w2f02 = g_all[384+lane], w2f03 = g_all[448+lane];
    h8 w2f10 = g_all[512+lane], w2f11 = g_all[576+lane], w2f12 = g_all[640+lane], w2f13 = g_all[704+lane];
    h8 wg2f0 = g_all[768+lane], wg2f1 = g_all[832+lane];

    const float b1c0 = b1[nn], b1c1 = b1[16+nn], b1c2 = b1[32+nn], b1c3 = b1[48+nn];
    const float b2c0 = b2[nn], b2c1 = b2[16+nn], b2c2 = b2[32+nn], b2c3 = b2[48+nn];
    const float bgc0 = bg1[nn], bgc1 = bg1[16+nn], bgc2 = bg1[32+nn], bgc3 = bg1[48+nn];
    const float fg00 = fgam[nn], fg01 = fgam[16+nn], fg02 = fgam[32+nn], fg03 = fgam[48+nn];
    const float fg10 = fgam[64+nn], fg11 = fgam[80+nn], fg12 = fgam[96+nn], fg13 = fgam[112+nn];
    const float fb00 = fbet[nn], fb01 = fbet[16+nn], fb02 = fbet[32+nn], fb03 = fbet[48+nn];
    const float fb10 = fbet[64+nn], fb11 = fbet[80+nn], fb12 = fbet[96+nn], fb13 = fbet[112+nn];
    const float gw0 = lng[nn]*Wo[nn], gw1 = lng[16+nn]*Wo[16+nn];
    const float gw2 = lng[32+nn]*Wo[32+nn], gw3 = lng[48+nn]*Wo[48+nn];
    const float s0 = __expf(lscale[0]), s1 = __expf(lscale[1]);
    const float invT = __expf(-gt[0]);
    const float outc = g_cc[0] + bo[0], C1 = g_cc[1];
    const float lgb = (nn < 2) ? bg2[nn] : 0.f;

    const int wgid = blockIdx.x*4 + wave;

    for (int it = 0; it < ITERS; ++it) {
        const int T = wgid + it*(BLOCKS*4);
        const int p0 = T*16;
        const int bb = p0 >> 16, ii = (p0 >> 8) & 255, j0 = p0 & 255;
        // ---- features: lanes 0-15 cost channel, 16-31 angle channel ----
        const float xc = cost[p0 + nn];
        const float* cb = coords + (bb << 9);
        const float xi = cb[2*ii], yi = cb[2*ii+1];
        const float xj = cb[2*(j0+nn)], yj = cb[2*(j0+nn)+1];
        const float ang = atan2f(yi - yj, xi - xj);
        const int isA = q & 1;
        const float xv = isA ? ang : xc;
        const float sE = isA ? s1 : s0;
        const float F0 = xv*sE;
        const float sn1 = __sinf(xv)*sE,      cs1 = __cosf(xv)*sE;
        const float sn2 = __sinf(2.f*xv)*sE,  cs2 = __cosf(2.f*xv)*sE;
        const float sn4 = __sinf(4.f*xv)*sE,  cs4 = __cosf(4.f*xv)*sE;
        const float sn8 = __sinf(8.f*xv)*sE,  cs8 = __cosf(8.f*xv)*sE;
        if (lane < 32) {
            // full 32-half zero-padded row: pads rewritten every iter (region aliased)
            _Float16* fp = U + isA*640 + nn*40;
            h8 r0; r0[0]=(_Float16)F0;  r0[1]=(_Float16)sn1; r0[2]=(_Float16)cs1;
                   r0[3]=(_Float16)sn2; r0[4]=(_Float16)cs2; r0[5]=(_Float16)sn4;
                   r0[6]=(_Float16)cs4; r0[7]=(_Float16)sn8;
            h8 rz = (h8)(_Float16)0.f;
            h8 r1 = rz; r1[0]=(_Float16)cs8;
            *(h8*)(fp)    = r0; *(h8*)(fp+8)  = r1;
            *(h8*)(fp+16) = rz; *(h8*)(fp+24) = rz;
        }
        // ---- L1: feats(16 pad 32) @ W1 -> silu -> h tile (aliases feat) ----
        h8 aF0 = *(h8*)(U + nn*40 + q*8);
        h8 aF1 = *(h8*)(U + 640 + nn*40 + q*8);
        _Float16* hw0 = U + q*288 + nn;
        _Float16* hw1 = U + 1152 + q*288 + nn;
        { f4 a = {b1c0,b1c0,b1c0,b1c0}; a = MFMA(aF0, w1f0, a); st72(hw0,    silu4(a)); }
        { f4 a = {b1c1,b1c1,b1c1,b1c1}; a = MFMA(aF0, w1f1, a); st72(hw0+16, silu4(a)); }
        { f4 a = {b1c2,b1c2,b1c2,b1c2}; a = MFMA(aF0, w1f2, a); st72(hw0+32, silu4(a)); }
        { f4 a = {b1c3,b1c3,b1c3,b1c3}; a = MFMA(aF0, w1f3, a); st72(hw0+48, silu4(a)); }
        { f4 a = {b1c0,b1c0,b1c0,b1c0}; a = MFMA(aF1, w1f0, a); st72(hw1,    silu4(a)); }
        { f4 a = {b1c1,b1c1,b1c1,b1c1}; a = MFMA(aF1, w1f1, a); st72(hw1+16, silu4(a)); }
        { f4 a = {b1c2,b1c2,b1c2,b1c2}; a = MFMA(aF1, w1f2, a); st72(hw1+32, silu4(a)); }
        { f4 a = {b1c3,b1c3,b1c3,b1c3}; a = MFMA(aF1, w1f3, a); st72(hw1+48, silu4(a)); }
        // ---- L2: h @ W2 + b2, FiLM; e in f32 frags + f16 into U (aliases h) ----
        h8 a00 = *(h8*)(U + nn*72 + q*8);
        h8 a01 = *(h8*)(U + nn*72 + 32 + q*8);
        h8 a10 = *(h8*)(U + 1152 + nn*72 + q*8);
        h8 a11 = *(h8*)(U + 1152 + nn*72 + 32 + q*8);
        _Float16* ew = U + q*544 + nn;
        f4 e00,e01,e02,e03,e10,e11,e12,e13;
        { f4 a={b2c0,b2c0,b2c0,b2c0}; a=MFMA(a00,w2f00,a); a=MFMA(a01,w2f10,a); e00=a*fg00+fb00; st136(ew,     e00); }
        { f4 a={b2c1,b2c1,b2c1,b2c1}; a=MFMA(a00,w2f01,a); a=MFMA(a01,w2f11,a); e01=a*fg01+fb01; st136(ew+16,  e01); }
        { f4 a={b2c2,b2c2,b2c2,b2c2}; a=MFMA(a00,w2f02,a); a=MFMA(a01,w2f12,a); e02=a*fg02+fb02; st136(ew+32,  e02); }
        { f4 a={b2c3,b2c3,b2c3,b2c3}; a=MFMA(a00,w2f03,a); a=MFMA(a01,w2f13,a); e03=a*fg03+fb03; st136(ew+48,  e03); }
        { f4 a={b2c0,b2c0,b2c0,b2c0}; a=MFMA(a10,w2f00,a); a=MFMA(a11,w2f10,a); e10=a*fg10+fb10; st136(ew+64,  e10); }
        { f4 a={b2c1,b2c1,b2c1,b2c1}; a=MFMA(a10,w2f01,a); a=MFMA(a11,w2f11,a); e11=a*fg11+fb11; st136(ew+80,  e11); }
        { f4 a={b2c2,b2c2,b2c2,b2c2}; a=MFMA(a10,w2f02,a); a=MFMA(a11,w2f12,a); e12=a*fg12+fb12; st136(ew+96,  e12); }
        { f4 a={b2c3,b2c3,b2c3,b2c3}; a=MFMA(a10,w2f03,a); a=MFMA(a11,w2f13,a); e13=a*fg13+fb13; st136(ew+112, e13); }
        // ---- gate1: [e0|e1] @ Wg1 + bg1 -> silu -> g tile (aliases e) ----
        h8 ae0 = *(h8*)(U + nn*136 + q*8);
        h8 ae1 = *(h8*)(U + nn*136 + 32 + q*8);
        h8 ae2 = *(h8*)(U + nn*136 + 64 + q*8);
        h8 ae3 = *(h8*)(U + nn*136 + 96 + q*8);
        _Float16* gw_ = U + q*288 + nn;
        { f4 a={bgc0,bgc0,bgc0,bgc0}; a=MFMA(ae0,wgv[lane],a);     a=MFMA(ae1,wgv[256+lane],a); a=MFMA(ae2,wgv[512+lane],a); a=MFMA(ae3,wgv[768+lane],a); st72(gw_,    silu4(a)); }
        { f4 a={bgc1,bgc1,bgc1,bgc1}; a=MFMA(ae0,wgv[64+lane],a);  a=MFMA(ae1,wgv[320+lane],a); a=MFMA(ae2,wgv[576+lane],a); a=MFMA(ae3,wgv[832+lane],a); st72(gw_+16, silu4(a)); }
        { f4 a={bgc2,bgc2,bgc2,bgc2}; a=MFMA(ae0,wgv[128+lane],a); a=MFMA(ae1,wgv[384+lane],a); a=MFMA(ae2,wgv[640+lane],a); a=MFMA(ae3,wgv[896+lane],a); st72(gw_+32, silu4(a)); }
        { f4 a={bgc3,bgc3,bgc3,bgc3}; a=MFMA(ae0,wgv[192+lane],a); a=MFMA(ae1,wgv[448+lane],a); a=MFMA(ae2,wgv[704+lane],a); a=MFMA(ae3,wgv[960+lane],a); st72(gw_+48, silu4(a)); }
        // ---- gate2: g @ Wg2 (N pad 16); logits broadcast via shfl ----
        h8 ag0 = *(h8*)(U + nn*72 + q*8);
        h8 ag1 = *(h8*)(U + nn*72 + 32 + q*8);
        f4 lg = {lgb, lgb, lgb, lgb};
        lg = MFMA(ag0, wg2f0, lg); lg = MFMA(ag1, wg2f1, lg);
        const int sb = lane & 48;
        f4 w1v;
        w1v[0] = sig((__shfl(lg[0], sb|1) - __shfl(lg[0], sb))*invT);
        w1v[1] = sig((__shfl(lg[1], sb|1) - __shfl(lg[1], sb))*invT);
        w1v[2] = sig((__shfl(lg[2], sb|1) - __shfl(lg[2], sb))*invT);
        w1v[3] = sig((__shfl(lg[3], sb|1) - __shfl(lg[3], sb))*invT);
        // ---- fuse + LayerNorm + head (var = E[x^2] - mu^2) ----
        f4 fu0 = e00 + w1v*(e10-e00);
        f4 fu1 = e01 + w1v*(e11-e01);
        f4 fu2 = e02 + w1v*(e12-e02);
        f4 fu3 = e03 + w1v*(e13-e03);
        f4 sv = reduce16((fu0+fu1)+(fu2+fu3));
        f4 sq = reduce16((fu0*fu0+fu1*fu1)+(fu2*fu2+fu3*fu3));
        f4 dt = reduce16((fu0*gw0 + fu1*gw1) + (fu2*gw2 + fu3*gw3));
        f4 mu = sv * (1.f/64.f);
        f4 vv = sq * (1.f/64.f) - mu*mu;
        f4 rs;
        rs[0] = __builtin_amdgcn_rsqf(vv[0]+1e-5f); rs[1] = __builtin_amdgcn_rsqf(vv[1]+1e-5f);
        rs[2] = __builtin_amdgcn_rsqf(vv[2]+1e-5f); rs[3] = __builtin_amdgcn_rsqf(vv[3]+1e-5f);
        f4 o = rs*(dt - mu*C1) + outc;
        if (nn == 0) *(f4*)(out + p0 + q*4) = o;
    }
}

extern "C" void kernel_launch(void* const* d_in, const int* in_sizes, int n_in,
                              void* d_out, int out_size, void* d_ws, size_t ws_size,
                              hipStream_t stream)
{
    const float* coords = (const float*)d_in[0];
    const float* cost   = (const float*)d_in[1];
    const float* lscale = (const float*)d_in[2];
    const float* W1     = (const float*)d_in[3];
    const float* b1     = (const float*)d_in[4];
    const float* W2     = (const float*)d_in[5];
    const float* b2     = (const float*)d_in[6];
    const float* fg     = (const float*)d_in[7];
    const float* fb     = (const float*)d_in[8];
    const float* Wg1    = (const float*)d_in[9];
    const float* bg1    = (const float*)d_in[10];
    const float* Wg2    = (const float*)d_in[11];
    const float* bg2    = (const float*)d_in[12];
    const float* gt     = (const float*)d_in[13];
    const float* lng    = (const float*)d_in[14];
    const float* lnb    = (const float*)d_in[15];
    const float* Wo     = (const float*)d_in[16];
    const float* bo     = (const float*)d_in[17];
    float* out = (float*)d_out;

    prep_kernel<<<8, 256, 0, stream>>>(W1, W2, Wg1, Wg2, lng, lnb, Wo);
    fused_kernel<<<BLOCKS, 256, 0, stream>>>(
        coords, cost, lscale, b1, b2, fg, fb, bg1, bg2, gt, lng, Wo, bo, out);
}

// Round 9
// 163.383 us; speedup vs baseline: 2.0362x; 1.1234x over previous
//
#include <hip/hip_runtime.h>
#include <math.h>

typedef _Float16 h8 __attribute__((ext_vector_type(8)));
typedef _Float16 h4 __attribute__((ext_vector_type(4)));
typedef float    f4 __attribute__((ext_vector_type(4)));

#define NPAIR (8*256*256)
#define NTILE (NPAIR/16)          // 32768 tiles of 16 rows
#define BLOCKS 2048
#define ITERS (NTILE/(BLOCKS*4))  // 4 tiles per wave

#define MFMA(a,b,c) __builtin_amdgcn_mfma_f32_16x16x32_f16((a),(b),(c),0,0,0)

// Weight fragments (h8 units). k-indices of W2/Wg1 are PERMUTED to match the
// packed LDS layouts (reduction order over k is arbitrary as long as A and B
// agree):
//   h tile:  position p = (u%16)*4 + u/16        (u = hidden 0..63)
//   e tile:  position p = (u%16)*8 + (u/64)*4 + (u/16)%4   (u = 0..127)
// [0,256)    W1   [t*64+lane]   k 9..31 zero-padded (natural k order)
// [256,768)  W2   [c*256+t*64+lane]   k = k_h(32c+8q+j)
// [768,896)  unused
// [896,1920) Wg1  [c*256+t*64+lane]   k = k_e(32c+8q+j)
__device__ h8 g_all[1920];
__device__ float g_cc[2];         // C0 = sum ln_b*Wo, C1 = sum ln_g*Wo

__global__ void prep_kernel(const float* __restrict__ W1, const float* __restrict__ W2,
                            const float* __restrict__ Wg1, const float* __restrict__ Wg2,
                            const float* __restrict__ ln_g, const float* __restrict__ ln_b,
                            const float* __restrict__ Wo)
{
    int idx = blockIdx.x * 256 + threadIdx.x;
    if (idx < 256) {
        int t = idx >> 6, lane = idx & 63, q = lane >> 4, nn = lane & 15;
        h8 v;
#pragma unroll
        for (int j = 0; j < 8; ++j) { int k = 8*q + j; v[j] = (_Float16)((k < 9) ? W1[k*64 + 16*t + nn] : 0.f); }
        g_all[idx] = v;
    } else if (idx < 768) {
        int z = idx - 256; int c = z >> 8, t = (z >> 6) & 3, lane = z & 63, q = lane >> 4, nn = lane & 15;
        h8 v;
#pragma unroll
        for (int j = 0; j < 8; ++j) {
            int p = 32*c + 8*q + j;                 // position in packed h tile
            int k = (p >> 2) + 16*(p & 3);          // logical hidden index
            v[j] = (_Float16)W2[k*64 + 16*t + nn];
        }
        g_all[idx] = v;
    } else if (idx >= 896 && idx < 1920) {
        int z = idx - 896; int c = z >> 8, t = (z >> 6) & 3, lane = z & 63, q = lane >> 4, nn = lane & 15;
        h8 v;
#pragma unroll
        for (int j = 0; j < 8; ++j) {
            int p = 32*c + 8*q + j;                 // position in packed e tile
            int k = ((p >> 2) & 1)*64 + (p & 3)*16 + (p >> 3);
            v[j] = (_Float16)Wg1[k*64 + 16*t + nn];
        }
        g_all[idx] = v;
    } else if (idx == 1920) {
        float c0 = 0.f, c1 = 0.f;
        for (int k = 0; k < 64; ++k) { c0 += ln_b[k]*Wo[k]; c1 += ln_g[k]*Wo[k]; }
        g_cc[0] = c0; g_cc[1] = c1;
    }
}

__device__ __forceinline__ float sig(float x) { return __builtin_amdgcn_rcpf(1.f + __expf(-x)); }

__device__ __forceinline__ f4 silu4(f4 v)
{
    f4 r; r[0] = v[0]*sig(v[0]); r[1] = v[1]*sig(v[1]); r[2] = v[2]*sig(v[2]); r[3] = v[3]*sig(v[3]);
    return r;
}

// 16-lane reduction on the VALU pipe via DPP row_ror (rows of 16 = our groups).
// Replaces ds_swizzle-based __shfl_xor (LDS pipe) — R8 analysis: LDS pipe is
// the binding resource, VALU has headroom (39% busy).
template<int C>
__device__ __forceinline__ float rora(float x)
{
    int y = __builtin_amdgcn_update_dpp(0, __float_as_int(x), C, 0xF, 0xF, true);
    return x + __int_as_float(y);
}
__device__ __forceinline__ float red16s(float x)
{
    x = rora<0x121>(x);  // row_ror:1
    x = rora<0x122>(x);  // row_ror:2
    x = rora<0x124>(x);  // row_ror:4
    x = rora<0x128>(x);  // row_ror:8
    return x;
}
__device__ __forceinline__ f4 red16(f4 v)
{ v[0] = red16s(v[0]); v[1] = red16s(v[1]); v[2] = red16s(v[2]); v[3] = red16s(v[3]); return v; }

// LDS: 16384 B Wg1 pool + 4 waves * 4608 B aliased feat/h/e scratch = 34816 B.
// Occupancy is register-limited to 2 waves/SIMD (R4-R8: AGPR+VGPR ~ 256/wave,
// unmovable without spill) — so this round cuts LDS-pipe work instead:
// packed b64/b128 C-frag stores (k-permuted weights), VALU gate2, DPP reduces.
__global__ __launch_bounds__(256, 2) void fused_kernel(
    const float* __restrict__ coords, const float* __restrict__ cost,
    const float* __restrict__ lscale, const float* __restrict__ b1,
    const float* __restrict__ b2, const float* __restrict__ fgam,
    const float* __restrict__ fbet, const float* __restrict__ bg1,
    const float* __restrict__ bg2, const float* __restrict__ Wg2,
    const float* __restrict__ gt, const float* __restrict__ lng,
    const float* __restrict__ Wo, const float* __restrict__ bo,
    float* __restrict__ out)
{
    __shared__ __align__(16) char smem[16384 + 4*4608];
    const int tid = threadIdx.x;
    const int wave = tid >> 6, lane = tid & 63;
    const int q = lane >> 4, nn = lane & 15;

    h8* wgv = (h8*)smem;                      // 1024 h8 = 16 KB: Wg1 frags
    for (int z = tid; z < 1024; z += 256) wgv[z] = g_all[896 + z];
    __syncthreads();

    _Float16* U = (_Float16*)(smem + 16384 + wave*4608);  // aliased feat/h/e

    // register-resident B-frags (48 VGPRs)
    h8 w1f0 = g_all[lane],      w1f1 = g_all[64+lane],  w1f2 = g_all[128+lane], w1f3 = g_all[192+lane];
    h8 w2f00 = g_all[256+lane], w2f01 = g_all[320+lane], w2f02 = g_all[384+lane], w2f03 = g_all[448+lane];
    h8 w2f10 = g_all[512+lane], w2f11 = g_all[576+lane], w2f12 = g_all[640+lane], w2f13 = g_all[704+lane];

    const float b1c0 = b1[nn], b1c1 = b1[16+nn], b1c2 = b1[32+nn], b1c3 = b1[48+nn];
    const float b2c0 = b2[nn], b2c1 = b2[16+nn], b2c2 = b2[32+nn], b2c3 = b2[48+nn];
    const float bgc0 = bg1[nn], bgc1 = bg1[16+nn], bgc2 = bg1[32+nn], bgc3 = bg1[48+nn];
    const float fg00 = fgam[nn], fg01 = fgam[16+nn], fg02 = fgam[32+nn], fg03 = fgam[48+nn];
    const float fg10 = fgam[64+nn], fg11 = fgam[80+nn], fg12 = fgam[96+nn], fg13 = fgam[112+nn];
    const float fb00 = fbet[nn], fb01 = fbet[16+nn], fb02 = fbet[32+nn], fb03 = fbet[48+nn];
    const float fb10 = fbet[64+nn], fb11 = fbet[80+nn], fb12 = fbet[96+nn], fb13 = fbet[112+nn];
    const float gw0 = lng[nn]*Wo[nn], gw1 = lng[16+nn]*Wo[16+nn];
    const float gw2 = lng[32+nn]*Wo[32+nn], gw3 = lng[48+nn]*Wo[48+nn];
    // gate2 folded to VALU: per-lane Wg2 column-diff, one per tile t
    const float wd0 = Wg2[nn*2+1]        - Wg2[nn*2];
    const float wd1 = Wg2[(16+nn)*2+1]   - Wg2[(16+nn)*2];
    const float wd2 = Wg2[(32+nn)*2+1]   - Wg2[(32+nn)*2];
    const float wd3 = Wg2[(48+nn)*2+1]   - Wg2[(48+nn)*2];
    const float dlgb = bg2[1] - bg2[0];
    const float s0 = __expf(lscale[0]), s1 = __expf(lscale[1]);
    const float invT = __expf(-gt[0]);
    const float outc = g_cc[0] + bo[0], C1 = g_cc[1];

    const int wgid = blockIdx.x*4 + wave;

    for (int it = 0; it < ITERS; ++it) {
        const int T = wgid + it*(BLOCKS*4);
        const int p0 = T*16;
        const int bb = p0 >> 16, ii = (p0 >> 8) & 255, j0 = p0 & 255;
        // ---- features: lanes 0-15 cost channel, 16-31 angle channel ----
        const float xc = cost[p0 + nn];
        const float* cb = coords + (bb << 9);
        const float xi = cb[2*ii], yi = cb[2*ii+1];
        const float xj = cb[2*(j0+nn)], yj = cb[2*(j0+nn)+1];
        const float ang = atan2f(yi - yj, xi - xj);
        const int isA = q & 1;
        const float xv = isA ? ang : xc;
        const float sE = isA ? s1 : s0;
        if (lane < 32) {
            _Float16* fp = U + isA*640 + nn*40;
            h8 r0; r0[0]=(_Float16)(xv*sE);
            r0[1]=(_Float16)(__sinf(xv)*sE);     r0[2]=(_Float16)(__cosf(xv)*sE);
            r0[3]=(_Float16)(__sinf(2.f*xv)*sE); r0[4]=(_Float16)(__cosf(2.f*xv)*sE);
            r0[5]=(_Float16)(__sinf(4.f*xv)*sE); r0[6]=(_Float16)(__cosf(4.f*xv)*sE);
            r0[7]=(_Float16)(__sinf(8.f*xv)*sE);
            h8 rz = (h8)(_Float16)0.f;
            h8 r1 = rz; r1[0]=(_Float16)(__cosf(8.f*xv)*sE);
            *(h8*)(fp)    = r0; *(h8*)(fp+8)  = r1;
            *(h8*)(fp+16) = rz; *(h8*)(fp+24) = rz;
        }
        // ---- L1: feats @ W1 -> silu -> packed h tile (position = (u%16)*4+u/16) ----
        h8 aF0 = *(h8*)(U + nn*40 + q*8);
        h8 aF1 = *(h8*)(U + 640 + nn*40 + q*8);
        {
            f4 c0={b1c0,b1c0,b1c0,b1c0}, c1={b1c1,b1c1,b1c1,b1c1};
            f4 c2={b1c2,b1c2,b1c2,b1c2}, c3={b1c3,b1c3,b1c3,b1c3};
            c0=MFMA(aF0,w1f0,c0); c1=MFMA(aF0,w1f1,c1); c2=MFMA(aF0,w1f2,c2); c3=MFMA(aF0,w1f3,c3);
            c0=silu4(c0); c1=silu4(c1); c2=silu4(c2); c3=silu4(c3);
            _Float16* hb = U + (q*4)*72 + nn*4;
#pragma unroll
            for (int r = 0; r < 4; ++r) {
                h4 pk; pk[0]=(_Float16)c0[r]; pk[1]=(_Float16)c1[r]; pk[2]=(_Float16)c2[r]; pk[3]=(_Float16)c3[r];
                *(h4*)(hb + r*72) = pk;            // ds_write_b64
            }
        }
        {
            f4 c0={b1c0,b1c0,b1c0,b1c0}, c1={b1c1,b1c1,b1c1,b1c1};
            f4 c2={b1c2,b1c2,b1c2,b1c2}, c3={b1c3,b1c3,b1c3,b1c3};
            c0=MFMA(aF1,w1f0,c0); c1=MFMA(aF1,w1f1,c1); c2=MFMA(aF1,w1f2,c2); c3=MFMA(aF1,w1f3,c3);
            c0=silu4(c0); c1=silu4(c1); c2=silu4(c2); c3=silu4(c3);
            _Float16* hb = U + 1152 + (q*4)*72 + nn*4;
#pragma unroll
            for (int r = 0; r < 4; ++r) {
                h4 pk; pk[0]=(_Float16)c0[r]; pk[1]=(_Float16)c1[r]; pk[2]=(_Float16)c2[r]; pk[3]=(_Float16)c3[r];
                *(h4*)(hb + r*72) = pk;
            }
        }
        // ---- L2: h @ W2' + b2, FiLM; e in f32 frags + packed f16 e tile ----
        h8 a00 = *(h8*)(U + nn*72 + q*8);
        h8 a01 = *(h8*)(U + nn*72 + 32 + q*8);
        h8 a10 = *(h8*)(U + 1152 + nn*72 + q*8);
        h8 a11 = *(h8*)(U + 1152 + nn*72 + 32 + q*8);
        f4 e00,e01,e02,e03,e10,e11,e12,e13;
        { f4 a={b2c0,b2c0,b2c0,b2c0}; a=MFMA(a00,w2f00,a); a=MFMA(a01,w2f10,a); e00=a*fg00+fb00; }
        { f4 a={b2c1,b2c1,b2c1,b2c1}; a=MFMA(a00,w2f01,a); a=MFMA(a01,w2f11,a); e01=a*fg01+fb01; }
        { f4 a={b2c2,b2c2,b2c2,b2c2}; a=MFMA(a00,w2f02,a); a=MFMA(a01,w2f12,a); e02=a*fg02+fb02; }
        { f4 a={b2c3,b2c3,b2c3,b2c3}; a=MFMA(a00,w2f03,a); a=MFMA(a01,w2f13,a); e03=a*fg03+fb03; }
        { f4 a={b2c0,b2c0,b2c0,b2c0}; a=MFMA(a10,w2f00,a); a=MFMA(a11,w2f10,a); e10=a*fg10+fb10; }
        { f4 a={b2c1,b2c1,b2c1,b2c1}; a=MFMA(a10,w2f01,a); a=MFMA(a11,w2f11,a); e11=a*fg11+fb11; }
        { f4 a={b2c2,b2c2,b2c2,b2c2}; a=MFMA(a10,w2f02,a); a=MFMA(a11,w2f12,a); e12=a*fg12+fb12; }
        { f4 a={b2c3,b2c3,b2c3,b2c3}; a=MFMA(a10,w2f03,a); a=MFMA(a11,w2f13,a); e13=a*fg13+fb13; }
        {
            _Float16* eb = U + (q*4)*136 + nn*8;   // position = (u%16)*8 + enc*4 + t
#pragma unroll
            for (int r = 0; r < 4; ++r) {
                h8 pk;
                pk[0]=(_Float16)e00[r]; pk[1]=(_Float16)e01[r]; pk[2]=(_Float16)e02[r]; pk[3]=(_Float16)e03[r];
                pk[4]=(_Float16)e10[r]; pk[5]=(_Float16)e11[r]; pk[6]=(_Float16)e12[r]; pk[7]=(_Float16)e13[r];
                *(h8*)(eb + r*136) = pk;           // ds_write_b128
            }
        }
        // ---- gate1: [e0|e1] @ Wg1' + bg1 -> silu; gate2 in VALU (no LDS) ----
        h8 ae0 = *(h8*)(U + nn*136 + q*8);
        h8 ae1 = *(h8*)(U + nn*136 + 32 + q*8);
        h8 ae2 = *(h8*)(U + nn*136 + 64 + q*8);
        h8 ae3 = *(h8*)(U + nn*136 + 96 + q*8);
        f4 g0={bgc0,bgc0,bgc0,bgc0}, g1={bgc1,bgc1,bgc1,bgc1};
        f4 g2={bgc2,bgc2,bgc2,bgc2}, g3={bgc3,bgc3,bgc3,bgc3};
        g0=MFMA(ae0,wgv[lane],g0);     g0=MFMA(ae1,wgv[256+lane],g0); g0=MFMA(ae2,wgv[512+lane],g0); g0=MFMA(ae3,wgv[768+lane],g0);
        g1=MFMA(ae0,wgv[64+lane],g1);  g1=MFMA(ae1,wgv[320+lane],g1); g1=MFMA(ae2,wgv[576+lane],g1); g1=MFMA(ae3,wgv[832+lane],g1);
        g2=MFMA(ae0,wgv[128+lane],g2); g2=MFMA(ae1,wgv[384+lane],g2); g2=MFMA(ae2,wgv[640+lane],g2); g2=MFMA(ae3,wgv[896+lane],g2);
        g3=MFMA(ae0,wgv[192+lane],g3); g3=MFMA(ae1,wgv[448+lane],g3); g3=MFMA(ae2,wgv[704+lane],g3); g3=MFMA(ae3,wgv[960+lane],g3);
        g0=silu4(g0); g1=silu4(g1); g2=silu4(g2); g3=silu4(g3);
        // logit diff per row: sum over 64 gate units = per-lane partial + red16
        f4 part = g0*wd0 + g1*wd1 + g2*wd2 + g3*wd3;
        f4 diff = red16(part);
        f4 w1v;
        w1v[0] = sig((diff[0]+dlgb)*invT); w1v[1] = sig((diff[1]+dlgb)*invT);
        w1v[2] = sig((diff[2]+dlgb)*invT); w1v[3] = sig((diff[3]+dlgb)*invT);
        // ---- fuse + LayerNorm + head (var = E[x^2] - mu^2), DPP reductions ----
        f4 fu0 = e00 + w1v*(e10-e00);
        f4 fu1 = e01 + w1v*(e11-e01);
        f4 fu2 = e02 + w1v*(e12-e02);
        f4 fu3 = e03 + w1v*(e13-e03);
        f4 sv = red16((fu0+fu1)+(fu2+fu3));
        f4 sq = red16((fu0*fu0+fu1*fu1)+(fu2*fu2+fu3*fu3));
        f4 dt = red16((fu0*gw0 + fu1*gw1) + (fu2*gw2 + fu3*gw3));
        f4 mu = sv * (1.f/64.f);
        f4 vv = sq * (1.f/64.f) - mu*mu;
        f4 rs;
        rs[0] = __builtin_amdgcn_rsqf(vv[0]+1e-5f); rs[1] = __builtin_amdgcn_rsqf(vv[1]+1e-5f);
        rs[2] = __builtin_amdgcn_rsqf(vv[2]+1e-5f); rs[3] = __builtin_amdgcn_rsqf(vv[3]+1e-5f);
        f4 o = rs*(dt - mu*C1) + outc;
        if (nn == 0) *(f4*)(out + p0 + q*4) = o;
    }
}

extern "C" void kernel_launch(void* const* d_in, const int* in_sizes, int n_in,
                              void* d_out, int out_size, void* d_ws, size_t ws_size,
                              hipStream_t stream)
{
    const float* coords = (const float*)d_in[0];
    const float* cost   = (const float*)d_in[1];
    const float* lscale = (const float*)d_in[2];
    const float* W1     = (const float*)d_in[3];
    const float* b1     = (const float*)d_in[4];
    const float* W2     = (const float*)d_in[5];
    const float* b2     = (const float*)d_in[6];
    const float* fg     = (const float*)d_in[7];
    const float* fb     = (const float*)d_in[8];
    const float* Wg1    = (const float*)d_in[9];
    const float* bg1    = (const float*)d_in[10];
    const float* Wg2    = (const float*)d_in[11];
    const float* bg2    = (const float*)d_in[12];
    const float* gt     = (const float*)d_in[13];
    const float* lng    = (const float*)d_in[14];
    const float* lnb    = (const float*)d_in[15];
    const float* Wo     = (const float*)d_in[16];
    const float* bo     = (const float*)d_in[17];
    float* out = (float*)d_out;

    prep_kernel<<<8, 256, 0, stream>>>(W1, W2, Wg1, Wg2, lng, lnb, Wo);
    fused_kernel<<<BLOCKS, 256, 0, stream>>>(
        coords, cost, lscale, b1, b2, fg, fb, bg1, bg2, Wg2, gt, lng, Wo, bo, out);
}